// Round 1
// baseline (195.960 us; speedup 1.0000x reference)
//
#include <hip/hip_runtime.h>

namespace {

constexpr int kCont  = 64;
constexpr int kNCate = 16;
constexpr int kEm    = 8;
constexpr int kRH    = 32;
constexpr int kR     = 32;
constexpr int kPH    = 16;
constexpr int kVocab = 1000;

__global__ __launch_bounds__(256) void fused_mlp(
    const float* __restrict__ x_cont,
    const int*   __restrict__ x_cate,
    const int*   __restrict__ t,
    const float* __restrict__ emb,
    const float* __restrict__ W1,
    const float* __restrict__ b1,
    const float* __restrict__ W2,
    const float* __restrict__ b2,
    const float* __restrict__ W3,
    const float* __restrict__ b3,
    const float* __restrict__ HW1,
    const float* __restrict__ Hb1,
    const float* __restrict__ HW2,
    const float* __restrict__ Hb2,
    float* __restrict__ out,
    int nrows)
{
    const int row = blockIdx.x * blockDim.x + threadIdx.x;
    if (row >= nrows) return;

    // ---------------- layer 1: h1 = relu(x @ W1 + b1), x = [x_cont | emb gathers] ----
    float h1[kRH];
#pragma unroll
    for (int j = 0; j < kRH; ++j) h1[j] = b1[j];

    // continuous part: 64 features, chunks of 8
    const float* xr = x_cont + (size_t)row * kCont;
#pragma unroll 2
    for (int k0 = 0; k0 < kCont; k0 += 8) {
        float4 a = *reinterpret_cast<const float4*>(xr + k0);
        float4 b = *reinterpret_cast<const float4*>(xr + k0 + 4);
        float xs[8] = {a.x, a.y, a.z, a.w, b.x, b.y, b.z, b.w};
        const float* w = W1 + (size_t)k0 * kRH;   // wave-uniform -> s_load
#pragma unroll
        for (int kk = 0; kk < 8; ++kk) {
#pragma unroll
            for (int j = 0; j < kRH; ++j)
                h1[j] = fmaf(xs[kk], w[kk * kRH + j], h1[j]);
        }
    }

    // embedding part: 16 categories x 8 dims
    const int* cr = x_cate + (size_t)row * kNCate;
#pragma unroll 2
    for (int c = 0; c < kNCate; ++c) {
        const int idx = cr[c];
        const float* ep = emb + ((size_t)c * kVocab + (size_t)idx) * kEm; // 32B aligned
        float4 a = *reinterpret_cast<const float4*>(ep);
        float4 b = *reinterpret_cast<const float4*>(ep + 4);
        float xs[8] = {a.x, a.y, a.z, a.w, b.x, b.y, b.z, b.w};
        const float* w = W1 + (size_t)(kCont + c * kEm) * kRH; // wave-uniform
#pragma unroll
        for (int kk = 0; kk < 8; ++kk) {
#pragma unroll
            for (int j = 0; j < kRH; ++j)
                h1[j] = fmaf(xs[kk], w[kk * kRH + j], h1[j]);
        }
    }

#pragma unroll
    for (int j = 0; j < kRH; ++j) h1[j] = fmaxf(h1[j], 0.0f);

    // ---------------- layer 2: h2 = relu(h1 @ W2 + b2) ----------------
    float h2[kRH];
#pragma unroll
    for (int j = 0; j < kRH; ++j) h2[j] = b2[j];
#pragma unroll 4
    for (int k = 0; k < kRH; ++k) {
        const float hk = h1[k];
        const float* w = W2 + (size_t)k * kRH;   // wave-uniform
#pragma unroll
        for (int j = 0; j < kRH; ++j)
            h2[j] = fmaf(hk, w[j], h2[j]);
    }
#pragma unroll
    for (int j = 0; j < kRH; ++j) h2[j] = fmaxf(h2[j], 0.0f);

    // ---------------- layer 3: r = h2 @ W3 + b3 ----------------
    float r[kR];
#pragma unroll
    for (int j = 0; j < kR; ++j) r[j] = b3[j];
#pragma unroll 4
    for (int k = 0; k < kRH; ++k) {
        const float hk = h2[k];
        const float* w = W3 + (size_t)k * kR;    // wave-uniform
#pragma unroll
        for (int j = 0; j < kR; ++j)
            r[j] = fmaf(hk, w[j], r[j]);
    }

    // ---------------- selected head: y = relu(r @ HW1[t] + Hb1[t]) @ HW2[t] + Hb2[t] --
    const int head = t[row];                              // divergent per lane
    const float* hw1 = HW1 + (size_t)head * kR * kPH;     // 2 KB/head, L1-resident
    const float* hb1 = Hb1 + (size_t)head * kPH;

    float hh[kPH];
#pragma unroll
    for (int j = 0; j < kPH; ++j) hh[j] = hb1[j];
#pragma unroll 4
    for (int k = 0; k < kR; ++k) {
        const float rk = r[k];
        const float* w = hw1 + (size_t)k * kPH;           // per-lane vector loads
#pragma unroll
        for (int j = 0; j < kPH; ++j)
            hh[j] = fmaf(rk, w[j], hh[j]);
    }

    const float* hw2 = HW2 + (size_t)head * kPH;
    float y = Hb2[head];
#pragma unroll
    for (int j = 0; j < kPH; ++j)
        y = fmaf(fmaxf(hh[j], 0.0f), hw2[j], y);

    out[row] = y;
}

} // namespace

extern "C" void kernel_launch(void* const* d_in, const int* in_sizes, int n_in,
                              void* d_out, int out_size, void* d_ws, size_t ws_size,
                              hipStream_t stream)
{
    const float* x_cont = (const float*)d_in[0];
    const int*   x_cate = (const int*)  d_in[1];
    const int*   t      = (const int*)  d_in[2];
    const float* emb    = (const float*)d_in[3];
    const float* W1     = (const float*)d_in[4];
    const float* b1     = (const float*)d_in[5];
    const float* W2     = (const float*)d_in[6];
    const float* b2     = (const float*)d_in[7];
    const float* W3     = (const float*)d_in[8];
    const float* b3     = (const float*)d_in[9];
    const float* HW1    = (const float*)d_in[10];
    const float* Hb1    = (const float*)d_in[11];
    const float* HW2    = (const float*)d_in[12];
    const float* Hb2    = (const float*)d_in[13];
    float* out = (float*)d_out;

    const int nrows = out_size;            // 524288
    const int block = 256;
    const int grid  = (nrows + block - 1) / block;   // 2048 blocks -> 8/CU
    hipLaunchKernelGGL(fused_mlp, dim3(grid), dim3(block), 0, stream,
                       x_cont, x_cate, t, emb, W1, b1, W2, b2, W3, b3,
                       HW1, Hb1, HW2, Hb2, out, nrows);
}